// Round 6
// baseline (140.603 us; speedup 1.0000x reference)
//
#include <hip/hip_runtime.h>
#include <math.h>

// Problem constants (from reference)
#define BB 64
#define TT 100
#define NN 20
#define NRR 380    // N*(N-1)
#define HR 190     // rows per block (half of NRR)

typedef float f32x4 __attribute__((ext_vector_type(4)));

__global__ __launch_bounds__(256) void gp_kernel(
    const float* __restrict__ state,    // (B,T,N,8)
    const float* __restrict__ shape,    // (B,T,N,4)
    const float* __restrict__ relinfo,  // (B,T,NR,3)
    float* __restrict__ out)
{
    const int blk  = blockIdx.x;      // 0..2*B*T-1
    const int bt   = blk >> 1;
    const int half = blk & 1;
    const int rb   = half * HR;       // global row base for this block
    const int tid  = threadIdx.x;

    __shared__ float  s_state[NN * 8];   // 640 B
    __shared__ float  s_shape[NN * 4];   // 320 B
    __shared__ float4 s_row4[HR * 5];    // 15.2 KB, output-linear
    __shared__ float  s_mask[HR];
    __shared__ int    s_ij[HR];

    const float THRESH  = 0.35f;
    const float HALF_PI = 1.57079632679489661923f; // float32(pi/2)

    // ---- phase 0: pre-issue relinfo for this thread's row; stage state/shape ----
    const int rc = (tid < HR) ? tid : 0;             // clamped local row
    const float* rbase = relinfo + ((size_t)bt * NRR + rb) * 3;
    const float ra0 = rbase[rc * 3 + 0];
    const float ra1 = rbase[rc * 3 + 1];
    const float ra2 = rbase[rc * 3 + 2];

    if (tid < NN * 8)                   s_state[tid]          = state[(size_t)bt * NN * 8 + tid];
    else if (tid < NN * 8 + NN * 4)     s_shape[tid - NN * 8] = shape[(size_t)bt * NN * 4 + (tid - NN * 8)];
    __syncthreads();

    const size_t REL_SZ = (size_t)BB * TT * NRR * 20;
    const size_t OBJ_SZ = (size_t)BB * TT * NN * 7;
    const size_t obase  = (size_t)bt * (NRR * 5) + (size_t)rb * 5;
    f32x4* relb  = (f32x4*)out                              + obase;
    float* objb  = out + REL_SZ                             + (size_t)bt * (NN * 7);
    f32x4* recvb = (f32x4*)(out + REL_SZ + OBJ_SZ)          + obase;
    f32x4* sendb = (f32x4*)(out + REL_SZ + OBJ_SZ + REL_SZ) + obase;

    // ---- obj_data: 140 consecutive floats per bt (half 0 only) ----
    if (half == 0 && tid < NN * 7) {
        const int n = tid / 7;
        const int c = tid - n * 7;
        float v;
        if (c < 2) {
            const float ang = s_state[n * 8 + 2];
            const float a   = (c == 0) ? ang : (ang + HALF_PI);
            v = cosf(a) * s_state[n * 8 + 3] + sinf(a) * s_state[n * 8 + 4];
        } else if (c == 2) {
            v = s_state[n * 8 + 5];
        } else {
            v = s_shape[n * 4 + (c - 3)];
        }
        objb[tid] = v;
    }

    // ---- phase 1: each of this block's 190 rel rows computed ONCE into LDS ----
    if (tid < HR) {
        const int r = rb + tid;              // global row
        const int i = r / 19;
        const int l = r - i * 19;
        const int j = (l < i) ? l : (l + 1);

        const float* si = &s_state[i * 8];
        const float* sj = &s_state[j * 8];

        const float dx = si[0] - sj[0];
        const float dy = si[1] - sj[1];
        const float d  = sqrtf(dx * dx + dy * dy);
        const float mask = (d < THRESH && d > 0.0f) ? 1.0f : 0.0f;

        const float dpx   = mask * (sj[0] - si[0]);
        const float dpy   = mask * (sj[1] - si[1]);
        const float adiff = mask * (sj[2] - si[2]);
        const float dvx   = mask * (sj[3] - si[3]);
        const float dvy   = mask * (sj[4] - si[4]);
        const float adv   = mask * (sj[5] - si[5]);
        const float cx    = mask * sj[6];
        const float cy    = mask * sj[7];

        const float rang = mask * si[2];
        const float c1 = cosf(rang),           s1 = sinf(rang);
        const float c2 = cosf(rang + HALF_PI), s2 = sinf(rang + HALF_PI);

        float4 w0, w1, w2, w3, w4;
        w0.x = ra0; w0.y = ra1; w0.z = ra2;
        w0.w = c1 * dpx + s1 * dpy;
        w1.x = c2 * dpx + s2 * dpy;
        w1.y = c1 * dvx + s1 * dvy;
        w1.z = c2 * dvx + s2 * dvy;
        w1.w = c1 * cx  + s1 * cy;
        w2.x = c2 * cx  + s2 * cy;
        w2.y = sinf(2.0f * adiff);
        w2.z = cosf(2.0f * adiff);   // == 1 when masked out, as in reference
        w2.w = adv;
        w3.x = mask * s_shape[i * 4 + 0];
        w3.y = mask * s_shape[i * 4 + 1];
        w3.z = mask * s_shape[i * 4 + 2];
        w3.w = mask * s_shape[i * 4 + 3];
        w4.x = mask * s_shape[j * 4 + 0];
        w4.y = mask * s_shape[j * 4 + 1];
        w4.z = mask * s_shape[j * 4 + 2];
        w4.w = mask * s_shape[j * 4 + 3];

        float4* row = &s_row4[tid * 5];
        row[0] = w0; row[1] = w1; row[2] = w2; row[3] = w3; row[4] = w4;
        s_mask[tid] = mask;
        s_ij[tid]   = i | (j << 8);
    }
    __syncthreads();

    // ---- phase 2: uniform 4-iter predicated blast (950 float4-quads), reads batched ----
    float4 w[4];
    float  m[4];
    int    ij[4];
#pragma unroll
    for (int k = 0; k < 4; ++k) {
        const int idx  = tid + k * 256;
        const int idxc = (idx < HR * 5) ? idx : 0;
        w[k]  = s_row4[idxc];
        m[k]  = s_mask[idxc / 5];
        ij[k] = s_ij[idxc / 5];
    }
#pragma unroll
    for (int k = 0; k < 4; ++k) {
        const int idx = tid + k * 256;
        if (idx < HR * 5) {
            const int rl = idx / 5;
            const int qb = (idx - rl * 5) * 4;
            const int i  = ij[k] & 255;
            const int j  = ij[k] >> 8;
            f32x4 wv, rv, sv;
            wv.x = w[k].x; wv.y = w[k].y; wv.z = w[k].z; wv.w = w[k].w;
            rv.x = (i == qb + 0) ? m[k] : 0.0f;
            rv.y = (i == qb + 1) ? m[k] : 0.0f;
            rv.z = (i == qb + 2) ? m[k] : 0.0f;
            rv.w = (i == qb + 3) ? m[k] : 0.0f;
            sv.x = (j == qb + 0) ? m[k] : 0.0f;
            sv.y = (j == qb + 1) ? m[k] : 0.0f;
            sv.z = (j == qb + 2) ? m[k] : 0.0f;
            sv.w = (j == qb + 3) ? m[k] : 0.0f;
            __builtin_nontemporal_store(wv, &relb[idx]);
            __builtin_nontemporal_store(rv, &recvb[idx]);
            __builtin_nontemporal_store(sv, &sendb[idx]);
        }
    }
}

extern "C" void kernel_launch(void* const* d_in, const int* in_sizes, int n_in,
                              void* d_out, int out_size, void* d_ws, size_t ws_size,
                              hipStream_t stream) {
    const float* state = (const float*)d_in[0];
    const float* shp   = (const float*)d_in[1];
    const float* rel   = (const float*)d_in[2];
    float* out = (float*)d_out;
    gp_kernel<<<dim3(BB * TT * 2), dim3(256), 0, stream>>>(state, shp, rel, out);
}

// Round 7
// 120.660 us; speedup vs baseline: 1.1653x; 1.1653x over previous
//
#include <hip/hip_runtime.h>
#include <math.h>

// Problem constants (from reference)
#define BB 64
#define TT 100
#define NN 20
#define NRR 380   // N*(N-1)

typedef float f32x4 __attribute__((ext_vector_type(4)));

// ---------------------------------------------------------------------------
// Kernel A: receiver_relations + sender_relations (one-hot * mask), 391 MB.
// Pure streaming: tiny LDS, no trig, two sequential single-stream store loops.
// ---------------------------------------------------------------------------
__global__ __launch_bounds__(256) void onehot_kernel(
    const float* __restrict__ state,    // (B,T,N,8)
    float* __restrict__ out)
{
    const int bt  = blockIdx.x;
    const int tid = threadIdx.x;

    __shared__ float s_pos[NN * 2];   // x,y per object
    __shared__ float s_mask[NRR];
    __shared__ int   s_ij[NRR];

    if (tid < NN * 2) {
        const int n = tid >> 1, c = tid & 1;
        s_pos[tid] = state[(size_t)bt * NN * 8 + n * 8 + c];
    }
    __syncthreads();

    const float THRESH = 0.35f;
    for (int r = tid; r < NRR; r += 256) {
        const int i = r / 19;
        const int l = r - i * 19;
        const int j = (l < i) ? l : (l + 1);
        const float dx = s_pos[i * 2 + 0] - s_pos[j * 2 + 0];
        const float dy = s_pos[i * 2 + 1] - s_pos[j * 2 + 1];
        const float d  = sqrtf(dx * dx + dy * dy);
        s_mask[r] = (d < THRESH && d > 0.0f) ? 1.0f : 0.0f;
        s_ij[r]   = i | (j << 8);
    }
    __syncthreads();

    const size_t REL_SZ = (size_t)BB * TT * NRR * 20;
    const size_t OBJ_SZ = (size_t)BB * TT * NN * 7;
    f32x4* recvb = (f32x4*)(out + REL_SZ + OBJ_SZ)          + (size_t)bt * (NRR * 5);
    f32x4* sendb = (f32x4*)(out + REL_SZ + OBJ_SZ + REL_SZ) + (size_t)bt * (NRR * 5);

    // ---- stream 1: all receiver quads for this bt ----
#pragma unroll
    for (int k = 0; k < 8; ++k) {
        const int idx = tid + k * 256;
        if (idx < NRR * 5) {
            const int r  = idx / 5;
            const int qb = (idx - r * 5) * 4;
            const float m = s_mask[r];
            const int   i = s_ij[r] & 255;
            f32x4 rv;
            rv.x = (i == qb + 0) ? m : 0.0f;
            rv.y = (i == qb + 1) ? m : 0.0f;
            rv.z = (i == qb + 2) ? m : 0.0f;
            rv.w = (i == qb + 3) ? m : 0.0f;
            __builtin_nontemporal_store(rv, &recvb[idx]);
        }
    }
    // ---- stream 2: all sender quads for this bt ----
#pragma unroll
    for (int k = 0; k < 8; ++k) {
        const int idx = tid + k * 256;
        if (idx < NRR * 5) {
            const int r  = idx / 5;
            const int qb = (idx - r * 5) * 4;
            const float m = s_mask[r];
            const int   j = s_ij[r] >> 8;
            f32x4 sv;
            sv.x = (j == qb + 0) ? m : 0.0f;
            sv.y = (j == qb + 1) ? m : 0.0f;
            sv.z = (j == qb + 2) ? m : 0.0f;
            sv.w = (j == qb + 3) ? m : 0.0f;
            __builtin_nontemporal_store(sv, &sendb[idx]);
        }
    }
}

// ---------------------------------------------------------------------------
// Kernel B: rel_data + obj_data (200 MB writes, 35 MB reads), LDS-staged rows.
// ---------------------------------------------------------------------------
__global__ __launch_bounds__(256) void reldata_kernel(
    const float* __restrict__ state,    // (B,T,N,8)
    const float* __restrict__ shape,    // (B,T,N,4)
    const float* __restrict__ relinfo,  // (B,T,NR,3)
    float* __restrict__ out)
{
    const int bt  = blockIdx.x;
    const int tid = threadIdx.x;

    __shared__ float  s_state[NN * 8];
    __shared__ float  s_shape[NN * 4];
    __shared__ float4 s_row4[NRR * 5];   // 30.4 KB, output-linear

    const float THRESH  = 0.35f;
    const float HALF_PI = 1.57079632679489661923f; // float32(pi/2)

    // pre-issue relinfo for this thread's rows
    const int   r2v = tid + 256;
    const int   r2c = (r2v < NRR) ? r2v : (NRR - 1);
    const float* rbase = relinfo + (size_t)bt * NRR * 3;
    const float ra0 = rbase[tid * 3 + 0];
    const float ra1 = rbase[tid * 3 + 1];
    const float ra2 = rbase[tid * 3 + 2];
    const float rb0 = rbase[r2c * 3 + 0];
    const float rb1 = rbase[r2c * 3 + 1];
    const float rb2 = rbase[r2c * 3 + 2];

    if (tid < NN * 8)                   s_state[tid]          = state[(size_t)bt * NN * 8 + tid];
    else if (tid < NN * 8 + NN * 4)     s_shape[tid - NN * 8] = shape[(size_t)bt * NN * 4 + (tid - NN * 8)];
    __syncthreads();

    const size_t REL_SZ = (size_t)BB * TT * NRR * 20;
    f32x4* relb = (f32x4*)out + (size_t)bt * (NRR * 5);
    float* objb = out + REL_SZ + (size_t)bt * (NN * 7);

    // ---- obj_data: 140 consecutive floats per bt ----
    if (tid < NN * 7) {
        const int n = tid / 7;
        const int c = tid - n * 7;
        float v;
        if (c < 2) {
            const float ang = s_state[n * 8 + 2];
            const float a   = (c == 0) ? ang : (ang + HALF_PI);
            v = cosf(a) * s_state[n * 8 + 3] + sinf(a) * s_state[n * 8 + 4];
        } else if (c == 2) {
            v = s_state[n * 8 + 5];
        } else {
            v = s_shape[n * 4 + (c - 3)];
        }
        objb[tid] = v;
    }

    // ---- phase 1: each rel row computed ONCE into LDS ----
    for (int pass = 0; pass < 2; ++pass) {
        const int r = (pass == 0) ? tid : r2v;
        if (r < NRR) {
            const float f0 = (pass == 0) ? ra0 : rb0;
            const float f1 = (pass == 0) ? ra1 : rb1;
            const float f2 = (pass == 0) ? ra2 : rb2;

            const int i = r / 19;
            const int l = r - i * 19;
            const int j = (l < i) ? l : (l + 1);

            const float* si = &s_state[i * 8];
            const float* sj = &s_state[j * 8];

            const float dx = si[0] - sj[0];
            const float dy = si[1] - sj[1];
            const float d  = sqrtf(dx * dx + dy * dy);
            const float mask = (d < THRESH && d > 0.0f) ? 1.0f : 0.0f;

            const float dpx   = mask * (sj[0] - si[0]);
            const float dpy   = mask * (sj[1] - si[1]);
            const float adiff = mask * (sj[2] - si[2]);
            const float dvx   = mask * (sj[3] - si[3]);
            const float dvy   = mask * (sj[4] - si[4]);
            const float adv   = mask * (sj[5] - si[5]);
            const float cx    = mask * sj[6];
            const float cy    = mask * sj[7];

            const float rang = mask * si[2];
            const float c1 = cosf(rang),           s1 = sinf(rang);
            const float c2 = cosf(rang + HALF_PI), s2 = sinf(rang + HALF_PI);

            float4 w0, w1, w2, w3, w4;
            w0.x = f0; w0.y = f1; w0.z = f2;
            w0.w = c1 * dpx + s1 * dpy;
            w1.x = c2 * dpx + s2 * dpy;
            w1.y = c1 * dvx + s1 * dvy;
            w1.z = c2 * dvx + s2 * dvy;
            w1.w = c1 * cx  + s1 * cy;
            w2.x = c2 * cx  + s2 * cy;
            w2.y = sinf(2.0f * adiff);
            w2.z = cosf(2.0f * adiff);   // == 1 when masked out, as in reference
            w2.w = adv;
            w3.x = mask * s_shape[i * 4 + 0];
            w3.y = mask * s_shape[i * 4 + 1];
            w3.z = mask * s_shape[i * 4 + 2];
            w3.w = mask * s_shape[i * 4 + 3];
            w4.x = mask * s_shape[j * 4 + 0];
            w4.y = mask * s_shape[j * 4 + 1];
            w4.z = mask * s_shape[j * 4 + 2];
            w4.w = mask * s_shape[j * 4 + 3];

            float4* row = &s_row4[r * 5];
            row[0] = w0; row[1] = w1; row[2] = w2; row[3] = w3; row[4] = w4;
        }
    }
    __syncthreads();

    // ---- phase 2: single-stream blast of rel quads ----
#pragma unroll
    for (int k = 0; k < 8; ++k) {
        const int idx = tid + k * 256;
        if (idx < NRR * 5) {
            const float4 w = s_row4[idx];
            f32x4 wv;
            wv.x = w.x; wv.y = w.y; wv.z = w.z; wv.w = w.w;
            __builtin_nontemporal_store(wv, &relb[idx]);
        }
    }
}

extern "C" void kernel_launch(void* const* d_in, const int* in_sizes, int n_in,
                              void* d_out, int out_size, void* d_ws, size_t ws_size,
                              hipStream_t stream) {
    const float* state = (const float*)d_in[0];
    const float* shp   = (const float*)d_in[1];
    const float* rel   = (const float*)d_in[2];
    float* out = (float*)d_out;
    reldata_kernel<<<dim3(BB * TT), dim3(256), 0, stream>>>(state, shp, rel, out);
    onehot_kernel <<<dim3(BB * TT), dim3(256), 0, stream>>>(state, out);
}

// Round 8
// 118.412 us; speedup vs baseline: 1.1874x; 1.0190x over previous
//
#include <hip/hip_runtime.h>
#include <math.h>

// Problem constants (from reference)
#define BB 64
#define TT 100
#define NN 20
#define NRR 380   // N*(N-1)
#define NBT (BB * TT)

typedef float f32x4 __attribute__((ext_vector_type(4)));

// One fused dispatch, role-grouped:
//   blocks [0,      NBT)   : rel_data + obj_data   (heavy pipeline, 1 stream)
//   blocks [NBT,  2*NBT)   : receiver_relations    (one-hot, 1 stream)
//   blocks [2*NBT,3*NBT)   : sender_relations      (one-hot, 1 stream)
__global__ __launch_bounds__(256) void fused_kernel(
    const float* __restrict__ state,    // (B,T,N,8)
    const float* __restrict__ shape,    // (B,T,N,4)
    const float* __restrict__ relinfo,  // (B,T,NR,3)
    float* __restrict__ out)
{
    const int blk  = blockIdx.x;
    const int role = blk / NBT;          // 0=rel, 1=recv, 2=send
    const int bt   = blk - role * NBT;
    const int tid  = threadIdx.x;

    const float THRESH  = 0.35f;
    const float HALF_PI = 1.57079632679489661923f; // float32(pi/2)

    const size_t REL_SZ = (size_t)NBT * NRR * 20;
    const size_t OBJ_SZ = (size_t)NBT * NN * 7;

    __shared__ float  s_state[NN * 8];
    __shared__ float  s_shape[NN * 4];
    __shared__ float4 s_row4[NRR * 5];   // 30.4 KB (rel role only)
    __shared__ float  s_mask[NRR];
    __shared__ int    s_col[NRR];

    if (role == 0) {
        // ---------------- rel_data + obj_data ----------------
        // pre-issue relinfo for this thread's rows
        const int   r2v = tid + 256;
        const int   r2c = (r2v < NRR) ? r2v : (NRR - 1);
        const float* rbase = relinfo + (size_t)bt * NRR * 3;
        const float ra0 = rbase[tid * 3 + 0];
        const float ra1 = rbase[tid * 3 + 1];
        const float ra2 = rbase[tid * 3 + 2];
        const float rb0 = rbase[r2c * 3 + 0];
        const float rb1 = rbase[r2c * 3 + 1];
        const float rb2 = rbase[r2c * 3 + 2];

        if (tid < NN * 8)               s_state[tid]          = state[(size_t)bt * NN * 8 + tid];
        else if (tid < NN * 8 + NN * 4) s_shape[tid - NN * 8] = shape[(size_t)bt * NN * 4 + (tid - NN * 8)];
        __syncthreads();

        f32x4* relb = (f32x4*)out + (size_t)bt * (NRR * 5);
        float* objb = out + REL_SZ + (size_t)bt * (NN * 7);

        // obj_data: 140 consecutive floats per bt
        if (tid < NN * 7) {
            const int n = tid / 7;
            const int c = tid - n * 7;
            float v;
            if (c < 2) {
                const float ang = s_state[n * 8 + 2];
                const float a   = (c == 0) ? ang : (ang + HALF_PI);
                v = cosf(a) * s_state[n * 8 + 3] + sinf(a) * s_state[n * 8 + 4];
            } else if (c == 2) {
                v = s_state[n * 8 + 5];
            } else {
                v = s_shape[n * 4 + (c - 3)];
            }
            objb[tid] = v;
        }

        // each rel row computed ONCE into LDS
        for (int pass = 0; pass < 2; ++pass) {
            const int r = (pass == 0) ? tid : r2v;
            if (r < NRR) {
                const float f0 = (pass == 0) ? ra0 : rb0;
                const float f1 = (pass == 0) ? ra1 : rb1;
                const float f2 = (pass == 0) ? ra2 : rb2;

                const int i = r / 19;
                const int l = r - i * 19;
                const int j = (l < i) ? l : (l + 1);

                const float* si = &s_state[i * 8];
                const float* sj = &s_state[j * 8];

                const float dx = si[0] - sj[0];
                const float dy = si[1] - sj[1];
                const float d  = sqrtf(dx * dx + dy * dy);
                const float mask = (d < THRESH && d > 0.0f) ? 1.0f : 0.0f;

                const float dpx   = mask * (sj[0] - si[0]);
                const float dpy   = mask * (sj[1] - si[1]);
                const float adiff = mask * (sj[2] - si[2]);
                const float dvx   = mask * (sj[3] - si[3]);
                const float dvy   = mask * (sj[4] - si[4]);
                const float adv   = mask * (sj[5] - si[5]);
                const float cx    = mask * sj[6];
                const float cy    = mask * sj[7];

                const float rang = mask * si[2];
                const float c1 = cosf(rang),           s1 = sinf(rang);
                const float c2 = cosf(rang + HALF_PI), s2 = sinf(rang + HALF_PI);

                float4 w0, w1, w2, w3, w4;
                w0.x = f0; w0.y = f1; w0.z = f2;
                w0.w = c1 * dpx + s1 * dpy;
                w1.x = c2 * dpx + s2 * dpy;
                w1.y = c1 * dvx + s1 * dvy;
                w1.z = c2 * dvx + s2 * dvy;
                w1.w = c1 * cx  + s1 * cy;
                w2.x = c2 * cx  + s2 * cy;
                w2.y = sinf(2.0f * adiff);
                w2.z = cosf(2.0f * adiff);   // == 1 when masked out, as in reference
                w2.w = adv;
                w3.x = mask * s_shape[i * 4 + 0];
                w3.y = mask * s_shape[i * 4 + 1];
                w3.z = mask * s_shape[i * 4 + 2];
                w3.w = mask * s_shape[i * 4 + 3];
                w4.x = mask * s_shape[j * 4 + 0];
                w4.y = mask * s_shape[j * 4 + 1];
                w4.z = mask * s_shape[j * 4 + 2];
                w4.w = mask * s_shape[j * 4 + 3];

                float4* row = &s_row4[r * 5];
                row[0] = w0; row[1] = w1; row[2] = w2; row[3] = w3; row[4] = w4;
            }
        }
        __syncthreads();

        // single-stream blast of rel quads (plain stores)
#pragma unroll
        for (int k = 0; k < 8; ++k) {
            const int idx = tid + k * 256;
            if (idx < NRR * 5) {
                const float4 w = s_row4[idx];
                f32x4 wv;
                wv.x = w.x; wv.y = w.y; wv.z = w.z; wv.w = w.w;
                relb[idx] = wv;
            }
        }
    } else {
        // ---------------- one-hot region (recv or send) ----------------
        if (tid < NN * 2) {
            const int n = tid >> 1, c = tid & 1;
            s_state[tid] = state[(size_t)bt * NN * 8 + n * 8 + c];  // reuse s_state as s_pos
        }
        __syncthreads();

        for (int r = tid; r < NRR; r += 256) {
            const int i = r / 19;
            const int l = r - i * 19;
            const int j = (l < i) ? l : (l + 1);
            const float dx = s_state[i * 2 + 0] - s_state[j * 2 + 0];
            const float dy = s_state[i * 2 + 1] - s_state[j * 2 + 1];
            const float d  = sqrtf(dx * dx + dy * dy);
            s_mask[r] = (d < THRESH && d > 0.0f) ? 1.0f : 0.0f;
            s_col[r]  = (role == 1) ? i : j;
        }
        __syncthreads();

        f32x4* dst = (f32x4*)(out + REL_SZ + OBJ_SZ + (size_t)(role - 1) * REL_SZ)
                     + (size_t)bt * (NRR * 5);

        // single-stream blast of one-hot quads (plain stores)
#pragma unroll
        for (int k = 0; k < 8; ++k) {
            const int idx = tid + k * 256;
            if (idx < NRR * 5) {
                const int r  = idx / 5;
                const int qb = (idx - r * 5) * 4;
                const float m = s_mask[r];
                const int   c = s_col[r];
                f32x4 v;
                v.x = (c == qb + 0) ? m : 0.0f;
                v.y = (c == qb + 1) ? m : 0.0f;
                v.z = (c == qb + 2) ? m : 0.0f;
                v.w = (c == qb + 3) ? m : 0.0f;
                dst[idx] = v;
            }
        }
    }
}

extern "C" void kernel_launch(void* const* d_in, const int* in_sizes, int n_in,
                              void* d_out, int out_size, void* d_ws, size_t ws_size,
                              hipStream_t stream) {
    const float* state = (const float*)d_in[0];
    const float* shp   = (const float*)d_in[1];
    const float* rel   = (const float*)d_in[2];
    float* out = (float*)d_out;
    fused_kernel<<<dim3(NBT * 3), dim3(256), 0, stream>>>(state, shp, rel, out);
}